// Round 2
// baseline (10036.263 us; speedup 1.0000x reference)
//
#include <hip/hip_runtime.h>
#include <cstddef>
#include <cstdint>

// Problem constants (from reference)
#define SEQB   8
#define SEQL   2048
#define DMODEL 1024
#define DINNER 2048
#define DSTATE 16
#define MROWS  (SEQB*SEQL)   // 16384

__device__ __forceinline__ float siluf(float x){ return x / (1.f + __expf(-x)); }
__device__ __forceinline__ float softplusf(float x){ return (x > 20.f) ? x : log1pf(__expf(x)); }

// ---------------------------------------------------------------------------
// LayerNorm over last dim (1024), optional fused residual add (a + res).
// One block (256 thr) per row.
// ---------------------------------------------------------------------------
__global__ __launch_bounds__(256)
void ln_kernel(const float* __restrict__ a, const float* __restrict__ res,
               const float* __restrict__ w, const float* __restrict__ bias,
               float* __restrict__ out)
{
  int row = blockIdx.x;
  size_t off = (size_t)row * DMODEL;
  float4 v = ((const float4*)(a + off))[threadIdx.x];
  if (res){
    float4 u = ((const float4*)(res + off))[threadIdx.x];
    v.x += u.x; v.y += u.y; v.z += u.z; v.w += u.w;
  }
  float s  = v.x + v.y + v.z + v.w;
  float s2 = fmaf(v.x,v.x, fmaf(v.y,v.y, fmaf(v.z,v.z, v.w*v.w)));
  #pragma unroll
  for (int o=32;o>0;o>>=1){ s += __shfl_down(s,o,64); s2 += __shfl_down(s2,o,64); }
  __shared__ float red[8];
  int lane = threadIdx.x & 63, wid = threadIdx.x >> 6;
  if (lane==0){ red[wid]=s; red[4+wid]=s2; }
  __syncthreads();
  s  = red[0]+red[1]+red[2]+red[3];
  s2 = red[4]+red[5]+red[6]+red[7];
  float mu  = s * (1.f/DMODEL);
  float var = s2 * (1.f/DMODEL) - mu*mu;
  float rstd = rsqrtf(var + 1e-5f);
  float4 wv = ((const float4*)w)[threadIdx.x];
  float4 bv = ((const float4*)bias)[threadIdx.x];
  float4 o4;
  o4.x = (v.x-mu)*rstd*wv.x + bv.x;
  o4.y = (v.y-mu)*rstd*wv.y + bv.y;
  o4.z = (v.z-mu)*rstd*wv.z + bv.z;
  o4.w = (v.w-mu)*rstd*wv.w + bv.w;
  ((float4*)(out + off))[threadIdx.x] = o4;
}

// ---------------------------------------------------------------------------
// fp32 NT GEMM: C[m,n] = sum_k A[m*lda+k] * B[n*ldb+k]
// 128x128 tile, KT=16, 256 threads, 8x8 per thread.
// EPI==0: plain store
// EPI==1: C = softplus(C + ebias[n])                      (dt_proj)
// EPI==2: C = yb[m,n] * silu(C)                           (gating z-GEMM)
// ---------------------------------------------------------------------------
template<int EPI>
__global__ __launch_bounds__(256)
void gemm_nt(const float* __restrict__ A, int lda,
             const float* __restrict__ B, int ldb,
             float* __restrict__ C, int ldc,
             int N, int K,
             const float* __restrict__ ebias,
             const float* __restrict__ yb, int ldy)
{
  __shared__ float As[16][132];
  __shared__ float Bs[16][132];
  int tid = threadIdx.x;
  int tx = tid & 15, ty = tid >> 4;
  int mbase = blockIdx.y << 7;
  int nbase = blockIdx.x << 7;
  float acc[8][8];
  #pragma unroll
  for (int i=0;i<8;i++)
    #pragma unroll
    for (int j=0;j<8;j++) acc[i][j]=0.f;

  for (int k0=0;k0<K;k0+=16){
    #pragma unroll
    for (int it=0; it<2; it++){
      int idx = tid + (it<<8);     // 0..511
      int row = idx >> 2;          // 0..127
      int kq  = (idx & 3) << 2;    // 0,4,8,12
      float4 va = *(const float4*)(A + (size_t)(mbase+row)*lda + k0 + kq);
      As[kq+0][row]=va.x; As[kq+1][row]=va.y; As[kq+2][row]=va.z; As[kq+3][row]=va.w;
      int n = nbase + row;
      float4 vb = make_float4(0.f,0.f,0.f,0.f);
      if (n < N) vb = *(const float4*)(B + (size_t)n*ldb + k0 + kq);
      Bs[kq+0][row]=vb.x; Bs[kq+1][row]=vb.y; Bs[kq+2][row]=vb.z; Bs[kq+3][row]=vb.w;
    }
    __syncthreads();
    #pragma unroll
    for (int k=0;k<16;k++){
      float a[8], bb[8];
      *(float4*)&a[0]  = *(const float4*)&As[k][ty<<2];
      *(float4*)&a[4]  = *(const float4*)&As[k][64+(ty<<2)];
      *(float4*)&bb[0] = *(const float4*)&Bs[k][tx<<2];
      *(float4*)&bb[4] = *(const float4*)&Bs[k][64+(tx<<2)];
      #pragma unroll
      for (int i=0;i<8;i++)
        #pragma unroll
        for (int j=0;j<8;j++)
          acc[i][j] = fmaf(a[i], bb[j], acc[i][j]);
    }
    __syncthreads();
  }

  int n0 = nbase + (tx<<2);
  int n1 = n0 + 64;
  float4 eb0=make_float4(0,0,0,0), eb1=make_float4(0,0,0,0);
  if (EPI==1){
    if (n0 < N) eb0 = *(const float4*)(ebias + n0);
    if (n1 < N) eb1 = *(const float4*)(ebias + n1);
  }
  #pragma unroll
  for (int i=0;i<8;i++){
    int mrow = mbase + ((i<4) ? ((ty<<2)+i) : (64 + (ty<<2) + (i-4)));
    float4 c0 = make_float4(acc[i][0],acc[i][1],acc[i][2],acc[i][3]);
    float4 c1 = make_float4(acc[i][4],acc[i][5],acc[i][6],acc[i][7]);
    if (EPI==1){
      c0.x = softplusf(c0.x+eb0.x); c0.y = softplusf(c0.y+eb0.y);
      c0.z = softplusf(c0.z+eb0.z); c0.w = softplusf(c0.w+eb0.w);
      c1.x = softplusf(c1.x+eb1.x); c1.y = softplusf(c1.y+eb1.y);
      c1.z = softplusf(c1.z+eb1.z); c1.w = softplusf(c1.w+eb1.w);
    }
    if (EPI==2){
      if (n0 < N){
        float4 y0 = *(const float4*)(yb + (size_t)mrow*ldy + n0);
        c0.x = y0.x*siluf(c0.x); c0.y = y0.y*siluf(c0.y);
        c0.z = y0.z*siluf(c0.z); c0.w = y0.w*siluf(c0.w);
      }
      if (n1 < N){
        float4 y1 = *(const float4*)(yb + (size_t)mrow*ldy + n1);
        c1.x = y1.x*siluf(c1.x); c1.y = y1.y*siluf(c1.y);
        c1.z = y1.z*siluf(c1.z); c1.w = y1.w*siluf(c1.w);
      }
    }
    if (n0 < N) *(float4*)(C + (size_t)mrow*ldc + n0) = c0;
    if (n1 < N) *(float4*)(C + (size_t)mrow*ldc + n1) = c1;
  }
}

// ---------------------------------------------------------------------------
// Causal depthwise conv (k=4) + bias + SiLU. Each thread: 4 consecutive t,
// one d. Chunk-local: xi/xc point at NB batches. grid = NB*4096 blocks.
// ---------------------------------------------------------------------------
__global__ __launch_bounds__(256)
void conv_silu_kernel(const float* __restrict__ xi, const float* __restrict__ cw,
                      const float* __restrict__ cb, float* __restrict__ xc)
{
  int idx = blockIdx.x*256 + threadIdx.x;
  int d = idx & (DINNER-1);
  int g = idx >> 11;
  int t0 = (g & 511) << 2;    // 0..2044
  int b = g >> 9;             // 0..NB-1 (chunk-local)
  float4 w4 = *(const float4*)(cw + d*4);
  float bias = cb[d];
  const float* base = xi + (size_t)b*SEQL*DINNER + d;
  float v[7];
  #pragma unroll
  for (int j=0;j<7;j++){
    int t = t0-3+j;
    v[j] = (t>=0) ? base[(size_t)t*DINNER] : 0.f;
  }
  float* outp = xc + ((size_t)b*SEQL + t0)*DINNER + d;
  #pragma unroll
  for (int j=0;j<4;j++){
    float y = fmaf(v[j+3], w4.w, fmaf(v[j+2], w4.z, fmaf(v[j+1], w4.y, fmaf(v[j], w4.x, bias))));
    outp[(size_t)j*DINNER] = siluf(y);
  }
}

// ---------------------------------------------------------------------------
// Selective scan, one thread per (b,d) channel, chunk-local b.
// Reads u, dt (in dty), B/C from xdbl (cols 64..95, row stride 96).
// Writes y = scan_y + u*D IN-PLACE over dty (gating happens later in z-GEMM).
// u/dt prefetched 4 deep (HBM latency), B/C ping-pong 1 deep (L2-resident).
// grid = NB*32 blocks x 64 threads.
// ---------------------------------------------------------------------------
__global__ __launch_bounds__(64)
void scan_kernel(const float* __restrict__ u_, float* __restrict__ dty,
                 const float* __restrict__ xdbl,
                 const float* __restrict__ A_log, const float* __restrict__ Dp)
{
  int c = blockIdx.x*64 + threadIdx.x;
  int b = c >> 11, d = c & (DINNER-1);
  float A2[16];
  {
    const float* al = A_log + (size_t)d*DSTATE;
    #pragma unroll
    for (int s=0;s<16;s++) A2[s] = -expf(al[s]) * 1.44269504f;  // A * log2(e)
  }
  float Dv = Dp[d];
  float h[16];
  #pragma unroll
  for (int s=0;s<16;s++) h[s]=0.f;

  const float* pu  = u_  + (size_t)b*SEQL*DINNER + d;
  float*       pdt = dty + (size_t)b*SEQL*DINNER + d;
  const float* pbc = xdbl + (size_t)b*SEQL*96 + 64;

  float Bb[2][16], Cb[2][16];
#define LOAD_BC(buf, t) { const float4* p4 = (const float4*)(pbc + (size_t)(t)*96); \
    *(float4*)&Bb[buf][0]=p4[0]; *(float4*)&Bb[buf][4]=p4[1]; \
    *(float4*)&Bb[buf][8]=p4[2]; *(float4*)&Bb[buf][12]=p4[3]; \
    *(float4*)&Cb[buf][0]=p4[4]; *(float4*)&Cb[buf][4]=p4[5]; \
    *(float4*)&Cb[buf][8]=p4[6]; *(float4*)&Cb[buf][12]=p4[7]; }

  LOAD_BC(0, 0);
  float pu4[4], pdt4[4];
  #pragma unroll
  for (int j=0;j<4;j++){
    size_t o = (size_t)j*DINNER;
    pu4[j]=pu[o]; pdt4[j]=pdt[o];
  }

  for (int t0=0;t0<SEQL/4;t0++){
    #pragma unroll
    for (int kk=0;kk<4;kk++){
      int t = (t0<<2)+kk;
      const int cur = kk & 1, nxt = cur^1;
      float uc=pu4[kk], dtc=pdt4[kk];
      if (t+4 < SEQL){
        size_t o = (size_t)(t+4)*DINNER;
        pu4[kk]=pu[o]; pdt4[kk]=pdt[o];
      }
      if (t+1 < SEQL) LOAD_BC(nxt, t+1);
      float du = dtc*uc;
      float y = 0.f;
      #pragma unroll
      for (int s=0;s<16;s++){
        float dA = exp2f(dtc*A2[s]);
        h[s] = fmaf(dA, h[s], du*Bb[cur][s]);
        y = fmaf(h[s], Cb[cur][s], y);
      }
      y = fmaf(uc, Dv, y);
      pdt[(size_t)t*DINNER] = y;
    }
  }
#undef LOAD_BC
}

// ---------------------------------------------------------------------------
// Workspace-adaptive launcher. Processes NB batches per chunk (NB picked from
// ws_size). Per chunk, per layer:
//   LN -> H (in d_out)          [row-local, H rows die before out_proj writes]
//   in_proj(xi)  H x Wxi -> XI
//   conv+SiLU    XI -> XC
//   x_proj       XC -> XD (dt_low|B|C)
//   dt_proj+softplus  XD -> DT  (overwrites XI; xi dead after conv)
//   scan         u=XC, dt -> y in-place over DT
//   z-GEMM+gating H x Wz, out = y*silu(z) -> G (overwrites XC; u dead)
//   out_proj     G -> x1 (layer0, chunk-local) or d_out rows (layer1)
// ---------------------------------------------------------------------------
extern "C" void kernel_launch(void* const* d_in, const int* in_sizes, int n_in,
                              void* d_out, int out_size, void* d_ws, size_t ws_size,
                              hipStream_t stream)
{
  const float* x    = (const float*)d_in[0];
  const float* in_w = (const float*)d_in[1];
  const float* cw   = (const float*)d_in[2];
  const float* cb   = (const float*)d_in[3];
  const float* xpw  = (const float*)d_in[4];
  const float* dtw  = (const float*)d_in[5];
  const float* dtb  = (const float*)d_in[6];
  const float* A_log= (const float*)d_in[7];
  const float* Dp   = (const float*)d_in[8];
  const float* ow   = (const float*)d_in[9];
  const float* nw   = (const float*)d_in[10];
  const float* nb   = (const float*)d_in[11];
  float* outF = (float*)d_out;

  // Per-NB scratch bytes: XI + XC (each NB*2048*2048*4) + XD (NB*2048*96*4)
  // + X1 (NB*2048*1024*4)  = NB * 42,729,472 B
  int NB = 8;
  while (NB > 1 && (size_t)NB * 42729472ULL > ws_size) NB >>= 1;
  const int Mc = NB * SEQL;          // rows per chunk
  const int nchunk = SEQB / NB;

  float* ws = (float*)d_ws;
  float* XI = ws;                                   // Mc*2048  (xi -> dt -> y)
  float* XC = XI + (size_t)Mc*DINNER;               // Mc*2048  (u -> gated y)
  float* XD = XC + (size_t)Mc*DINNER;               // Mc*96    (dt_low|B|C)
  float* X1 = XD + (size_t)Mc*96;                   // Mc*1024  (layer-0 out)

  for (int c = 0; c < nchunk; ++c){
    const size_t rowoff = (size_t)c * Mc;
    const float* xrows = x + rowoff * DMODEL;
    float* H = outF + rowoff * DMODEL;              // d_out doubles as LN buf

    for (int l = 0; l < 2; ++l){
      const float* wl = in_w + (size_t)l*2*DINNER*DMODEL;

      // 1. LayerNorm (+ residual for layer 1)
      ln_kernel<<<Mc, 256, 0, stream>>>(
          (l==0) ? xrows : X1, (l==0) ? nullptr : xrows,
          nw + (size_t)l*DMODEL, nb + (size_t)l*DMODEL, H);

      // 2. in_proj xi half: (Mc x 1024) x (2048 x 1024)^T -> XI
      gemm_nt<0><<<dim3(16, Mc/128), 256, 0, stream>>>(
          H, DMODEL, wl, DMODEL, XI, DINNER, DINNER, DMODEL, nullptr, nullptr, 0);

      // 3. causal conv + bias + SiLU: XI -> XC
      conv_silu_kernel<<<NB*4096, 256, 0, stream>>>(
          XI, cw + (size_t)l*DINNER*4, cb + (size_t)l*DINNER, XC);

      // 4. x_proj: (Mc x 2048) x (96 x 2048)^T -> XD
      gemm_nt<0><<<dim3(1, Mc/128), 256, 0, stream>>>(
          XC, DINNER, xpw + (size_t)l*96*DINNER, DINNER, XD, 96, 96, DINNER,
          nullptr, nullptr, 0);

      // 5. dt_proj + bias + softplus: XD[:, :64] x (2048 x 64)^T -> DT (=XI)
      gemm_nt<1><<<dim3(16, Mc/128), 256, 0, stream>>>(
          XD, 96, dtw + (size_t)l*DINNER*64, 64, XI, DINNER, DINNER, 64,
          dtb + (size_t)l*DINNER, nullptr, 0);

      // 6. selective scan: y (+u*D) in-place over XI
      scan_kernel<<<NB*32, 64, 0, stream>>>(
          XC, XI, XD, A_log + (size_t)l*DINNER*DSTATE, Dp + (size_t)l*DINNER);

      // 7. z-GEMM + gating: z = H x Wz^T, G = y*silu(z) -> XC
      gemm_nt<2><<<dim3(16, Mc/128), 256, 0, stream>>>(
          H, DMODEL, wl + (size_t)DINNER*DMODEL, DMODEL, XC, DINNER,
          DINNER, DMODEL, nullptr, XI, DINNER);

      // 8. out_proj: (Mc x 2048) x (1024 x 2048)^T
      gemm_nt<0><<<dim3(8, Mc/128), 256, 0, stream>>>(
          XC, DINNER, ow + (size_t)l*DMODEL*DINNER, DINNER,
          (l==0) ? X1 : (outF + rowoff * DMODEL), DMODEL, DMODEL, DINNER,
          nullptr, nullptr, 0);
    }
  }
}

// Round 3
// 9450.442 us; speedup vs baseline: 1.0620x; 1.0620x over previous
//
#include <hip/hip_runtime.h>
#include <cstddef>
#include <cstdint>

// Problem constants (from reference)
#define SEQB   8
#define SEQL   2048
#define DMODEL 1024
#define DINNER 2048
#define DSTATE 16
#define MROWS  (SEQB*SEQL)   // 16384
#define NC     32            // scan chunks along t
#define TC     64            // SEQL/NC

__device__ __forceinline__ float siluf(float x){ return x / (1.f + __expf(-x)); }
__device__ __forceinline__ float softplusf(float x){ return (x > 20.f) ? x : log1pf(__expf(x)); }

// ---------------------------------------------------------------------------
// LayerNorm over last dim (1024), optional fused residual add (a + res).
// ---------------------------------------------------------------------------
__global__ __launch_bounds__(256)
void ln_kernel(const float* __restrict__ a, const float* __restrict__ res,
               const float* __restrict__ w, const float* __restrict__ bias,
               float* __restrict__ out)
{
  int row = blockIdx.x;
  size_t off = (size_t)row * DMODEL;
  float4 v = ((const float4*)(a + off))[threadIdx.x];
  if (res){
    float4 u = ((const float4*)(res + off))[threadIdx.x];
    v.x += u.x; v.y += u.y; v.z += u.z; v.w += u.w;
  }
  float s  = v.x + v.y + v.z + v.w;
  float s2 = fmaf(v.x,v.x, fmaf(v.y,v.y, fmaf(v.z,v.z, v.w*v.w)));
  #pragma unroll
  for (int o=32;o>0;o>>=1){ s += __shfl_down(s,o,64); s2 += __shfl_down(s2,o,64); }
  __shared__ float red[8];
  int lane = threadIdx.x & 63, wid = threadIdx.x >> 6;
  if (lane==0){ red[wid]=s; red[4+wid]=s2; }
  __syncthreads();
  s  = red[0]+red[1]+red[2]+red[3];
  s2 = red[4]+red[5]+red[6]+red[7];
  float mu  = s * (1.f/DMODEL);
  float var = s2 * (1.f/DMODEL) - mu*mu;
  float rstd = rsqrtf(var + 1e-5f);
  float4 wv = ((const float4*)w)[threadIdx.x];
  float4 bv = ((const float4*)bias)[threadIdx.x];
  float4 o4;
  o4.x = (v.x-mu)*rstd*wv.x + bv.x;
  o4.y = (v.y-mu)*rstd*wv.y + bv.y;
  o4.z = (v.z-mu)*rstd*wv.z + bv.z;
  o4.w = (v.w-mu)*rstd*wv.w + bv.w;
  ((float4*)(out + off))[threadIdx.x] = o4;
}

// ---------------------------------------------------------------------------
// fp32 NT GEMM: C[m,n] = sum_k A[m*lda+k] * B[n*ldb+k]
// 128x128 tile, KT=16, 256 threads, 8x8 per thread.
// EPI==0: plain   EPI==1: softplus(C+ebias[n])   EPI==2: yb[m,n]*silu(C)
// ---------------------------------------------------------------------------
template<int EPI>
__global__ __launch_bounds__(256)
void gemm_nt(const float* __restrict__ A, int lda,
             const float* __restrict__ B, int ldb,
             float* __restrict__ C, int ldc,
             int N, int K,
             const float* __restrict__ ebias,
             const float* __restrict__ yb, int ldy)
{
  __shared__ float As[16][132];
  __shared__ float Bs[16][132];
  int tid = threadIdx.x;
  int tx = tid & 15, ty = tid >> 4;
  int mbase = blockIdx.y << 7;
  int nbase = blockIdx.x << 7;
  float acc[8][8];
  #pragma unroll
  for (int i=0;i<8;i++)
    #pragma unroll
    for (int j=0;j<8;j++) acc[i][j]=0.f;

  for (int k0=0;k0<K;k0+=16){
    #pragma unroll
    for (int it=0; it<2; it++){
      int idx = tid + (it<<8);     // 0..511
      int row = idx >> 2;          // 0..127
      int kq  = (idx & 3) << 2;    // 0,4,8,12
      float4 va = *(const float4*)(A + (size_t)(mbase+row)*lda + k0 + kq);
      As[kq+0][row]=va.x; As[kq+1][row]=va.y; As[kq+2][row]=va.z; As[kq+3][row]=va.w;
      int n = nbase + row;
      float4 vb = make_float4(0.f,0.f,0.f,0.f);
      if (n < N) vb = *(const float4*)(B + (size_t)n*ldb + k0 + kq);
      Bs[kq+0][row]=vb.x; Bs[kq+1][row]=vb.y; Bs[kq+2][row]=vb.z; Bs[kq+3][row]=vb.w;
    }
    __syncthreads();
    #pragma unroll
    for (int k=0;k<16;k++){
      float a[8], bb[8];
      *(float4*)&a[0]  = *(const float4*)&As[k][ty<<2];
      *(float4*)&a[4]  = *(const float4*)&As[k][64+(ty<<2)];
      *(float4*)&bb[0] = *(const float4*)&Bs[k][tx<<2];
      *(float4*)&bb[4] = *(const float4*)&Bs[k][64+(tx<<2)];
      #pragma unroll
      for (int i=0;i<8;i++)
        #pragma unroll
        for (int j=0;j<8;j++)
          acc[i][j] = fmaf(a[i], bb[j], acc[i][j]);
    }
    __syncthreads();
  }

  int n0 = nbase + (tx<<2);
  int n1 = n0 + 64;
  float4 eb0=make_float4(0,0,0,0), eb1=make_float4(0,0,0,0);
  if (EPI==1){
    if (n0 < N) eb0 = *(const float4*)(ebias + n0);
    if (n1 < N) eb1 = *(const float4*)(ebias + n1);
  }
  #pragma unroll
  for (int i=0;i<8;i++){
    int mrow = mbase + ((i<4) ? ((ty<<2)+i) : (64 + (ty<<2) + (i-4)));
    float4 c0 = make_float4(acc[i][0],acc[i][1],acc[i][2],acc[i][3]);
    float4 c1 = make_float4(acc[i][4],acc[i][5],acc[i][6],acc[i][7]);
    if (EPI==1){
      c0.x = softplusf(c0.x+eb0.x); c0.y = softplusf(c0.y+eb0.y);
      c0.z = softplusf(c0.z+eb0.z); c0.w = softplusf(c0.w+eb0.w);
      c1.x = softplusf(c1.x+eb1.x); c1.y = softplusf(c1.y+eb1.y);
      c1.z = softplusf(c1.z+eb1.z); c1.w = softplusf(c1.w+eb1.w);
    }
    if (EPI==2){
      if (n0 < N){
        float4 y0 = *(const float4*)(yb + (size_t)mrow*ldy + n0);
        c0.x = y0.x*siluf(c0.x); c0.y = y0.y*siluf(c0.y);
        c0.z = y0.z*siluf(c0.z); c0.w = y0.w*siluf(c0.w);
      }
      if (n1 < N){
        float4 y1 = *(const float4*)(yb + (size_t)mrow*ldy + n1);
        c1.x = y1.x*siluf(c1.x); c1.y = y1.y*siluf(c1.y);
        c1.z = y1.z*siluf(c1.z); c1.w = y1.w*siluf(c1.w);
      }
    }
    if (n0 < N) *(float4*)(C + (size_t)mrow*ldc + n0) = c0;
    if (n1 < N) *(float4*)(C + (size_t)mrow*ldc + n1) = c1;
  }
}

// ---------------------------------------------------------------------------
// Causal depthwise conv (k=4) + bias + SiLU. grid = NB*4096 blocks.
// ---------------------------------------------------------------------------
__global__ __launch_bounds__(256)
void conv_silu_kernel(const float* __restrict__ xi, const float* __restrict__ cw,
                      const float* __restrict__ cb, float* __restrict__ xc)
{
  int idx = blockIdx.x*256 + threadIdx.x;
  int d = idx & (DINNER-1);
  int g = idx >> 11;
  int t0 = (g & 511) << 2;    // 0..2044
  int b = g >> 9;             // chunk-local batch
  float4 w4 = *(const float4*)(cw + d*4);
  float bias = cb[d];
  const float* base = xi + (size_t)b*SEQL*DINNER + d;
  float v[7];
  #pragma unroll
  for (int j=0;j<7;j++){
    int t = t0-3+j;
    v[j] = (t>=0) ? base[(size_t)t*DINNER] : 0.f;
  }
  float* outp = xc + ((size_t)b*SEQL + t0)*DINNER + d;
  #pragma unroll
  for (int j=0;j<4;j++){
    float y = fmaf(v[j+3], w4.w, fmaf(v[j+2], w4.z, fmaf(v[j+1], w4.y, fmaf(v[j], w4.x, bias))));
    outp[(size_t)j*DINNER] = siluf(y);
  }
}

// ---------------------------------------------------------------------------
// Chunked selective scan.
// PASS 1: local scan from h=0 over TC steps; store h_final[16] -> hfin and
//         sum(dt) -> sumdt  (chunk decay product = exp2(A2_s * sumdt)).
// PASS 3: local scan from h=hfin (now holding true chunk-initial state),
//         y = C.h + u*D written in-place over dt buffer.
// Thread = one (b, chunk, d). grid = NB*NC*8 blocks x 256.
// ---------------------------------------------------------------------------
template<int PASS>
__global__ __launch_bounds__(256)
void scan_chunk(const float* __restrict__ u_, float* __restrict__ dty,
                const float* __restrict__ xdbl,
                const float* __restrict__ A_log, const float* __restrict__ Dp,
                float* __restrict__ hfin, float* __restrict__ sumdt)
{
  int idx = blockIdx.x*256 + threadIdx.x;
  int d = idx & (DINNER-1);
  int g = idx >> 11;            // b*NC + c   (uniform per block)
  int c = g & (NC-1);
  int b = g >> 5;

  float A2[16];
  {
    const float* al = A_log + (size_t)d*DSTATE;
    #pragma unroll
    for (int s=0;s<16;s++) A2[s] = -expf(al[s]) * 1.44269504f;  // A*log2(e)
  }
  float h[16];
  if (PASS == 1){
    #pragma unroll
    for (int s=0;s<16;s++) h[s] = 0.f;
  } else {
    const float* hp = hfin + ((size_t)g*DINNER + d)*16;
    #pragma unroll
    for (int s=0;s<16;s+=4) *(float4*)&h[s] = *(const float4*)(hp + s);
  }
  float Dv = (PASS==3) ? Dp[d] : 0.f;

  size_t row0 = (size_t)b*SEQL + (size_t)c*TC;
  const float* pu  = u_  + row0*DINNER + d;
  float*       pdt = dty + row0*DINNER + d;
  const float* pbc = xdbl + row0*96 + 64;

  float sdt = 0.f;
  // 1-deep prefetch of the strided per-channel loads
  float dt_n = pdt[0];
  float u_n  = pu[0];

  for (int t=0; t<TC; t++){
    float dtc = dt_n, uc = u_n;
    if (t+1 < TC){
      dt_n = pdt[(size_t)(t+1)*DINNER];
      u_n  = pu [(size_t)(t+1)*DINNER];
    }
    float Bv[16], Cv[16];
    {
      const float4* p4 = (const float4*)(pbc + (size_t)t*96);
      *(float4*)&Bv[0]=p4[0]; *(float4*)&Bv[4]=p4[1];
      *(float4*)&Bv[8]=p4[2]; *(float4*)&Bv[12]=p4[3];
      if (PASS==3){
        *(float4*)&Cv[0]=p4[4]; *(float4*)&Cv[4]=p4[5];
        *(float4*)&Cv[8]=p4[6]; *(float4*)&Cv[12]=p4[7];
      }
    }
    if (PASS==1) sdt += dtc;
    float du = dtc*uc;
    float y = 0.f;
    #pragma unroll
    for (int s=0;s<16;s++){
      float dA = exp2f(dtc*A2[s]);
      h[s] = fmaf(dA, h[s], du*Bv[s]);
      if (PASS==3) y = fmaf(h[s], Cv[s], y);
    }
    if (PASS==3){
      y = fmaf(uc, Dv, y);
      pdt[(size_t)t*DINNER] = y;
    }
  }

  if (PASS==1){
    float* hp = hfin + ((size_t)g*DINNER + d)*16;
    #pragma unroll
    for (int s=0;s<16;s+=4) *(float4*)(hp + s) = *(const float4*)&h[s];
    sumdt[(size_t)g*DINNER + d] = sdt;
  }
}

// ---------------------------------------------------------------------------
// Propagate chunk-initial states: in-place hfin[c] := H_init(c).
// Thread = one (b,d,s). grid = NB*128 blocks x 256.
// ---------------------------------------------------------------------------
__global__ __launch_bounds__(256)
void scan_prop(const float* __restrict__ A_log, float* __restrict__ hfin,
               const float* __restrict__ sumdt)
{
  int idx = blockIdx.x*256 + threadIdx.x;   // b*32768 + d*16 + s
  int s = idx & 15;
  int d = (idx >> 4) & (DINNER-1);
  int b = idx >> 15;
  float A2 = -expf(A_log[(size_t)d*DSTATE + s]) * 1.44269504f;
  float H = 0.f;
  size_t hbase = ((size_t)b*NC*DINNER + d)*16 + s;   // chunk stride = DINNER*16
  size_t sbase = (size_t)b*NC*DINNER + d;            // chunk stride = DINNER
  for (int c=0;c<NC;c++){
    float P   = exp2f(A2 * sumdt[sbase + (size_t)c*DINNER]);
    float tmp = hfin[hbase + (size_t)c*DINNER*16];
    hfin[hbase + (size_t)c*DINNER*16] = H;
    H = fmaf(P, H, tmp);
  }
}

// ---------------------------------------------------------------------------
// Workspace-adaptive launcher. NB batches per chunk.
// Scratch per batch: XI 32MB + XC 32MB + XD 0.75MB + X1 8MB  (hfin/sumdt
// alias X1: X1 is dead during every scan at both layers).
// ---------------------------------------------------------------------------
extern "C" void kernel_launch(void* const* d_in, const int* in_sizes, int n_in,
                              void* d_out, int out_size, void* d_ws, size_t ws_size,
                              hipStream_t stream)
{
  const float* x    = (const float*)d_in[0];
  const float* in_w = (const float*)d_in[1];
  const float* cw   = (const float*)d_in[2];
  const float* cb   = (const float*)d_in[3];
  const float* xpw  = (const float*)d_in[4];
  const float* dtw  = (const float*)d_in[5];
  const float* dtb  = (const float*)d_in[6];
  const float* A_log= (const float*)d_in[7];
  const float* Dp   = (const float*)d_in[8];
  const float* ow   = (const float*)d_in[9];
  const float* nw   = (const float*)d_in[10];
  const float* nb   = (const float*)d_in[11];
  float* outF = (float*)d_out;

  // Per-batch scratch: XI+XC (2*16,777,216 floats? no: bytes) =
  // 2*2048*2048*4 + 2048*96*4 + 2048*1024*4 = 76,283,904 B
  int NB = 8;
  while (NB > 1 && (size_t)NB * 76283904ULL > ws_size) NB >>= 1;
  const int Mc = NB * SEQL;
  const int nchunk = SEQB / NB;

  float* ws = (float*)d_ws;
  float* XI = ws;                                   // Mc*2048 (xi -> dt -> y)
  float* XC = XI + (size_t)Mc*DINNER;               // Mc*2048 (u -> gated y)
  float* XD = XC + (size_t)Mc*DINNER;               // Mc*96   (dt_low|B|C)
  float* X1 = XD + (size_t)Mc*96;                   // Mc*1024 (layer-0 out)
  float* HF = X1;                                   // Mc*512  (hfin, aliases X1)
  float* SD = HF + (size_t)Mc*512;                  // Mc*32   (sumdt)

  for (int c = 0; c < nchunk; ++c){
    const size_t rowoff = (size_t)c * Mc;
    const float* xrows = x + rowoff * DMODEL;
    float* H = outF + rowoff * DMODEL;              // d_out doubles as LN buf

    for (int l = 0; l < 2; ++l){
      const float* wl = in_w + (size_t)l*2*DINNER*DMODEL;
      const float* Al = A_log + (size_t)l*DINNER*DSTATE;

      // 1. LayerNorm (+ residual for layer 1)
      ln_kernel<<<Mc, 256, 0, stream>>>(
          (l==0) ? xrows : X1, (l==0) ? nullptr : xrows,
          nw + (size_t)l*DMODEL, nb + (size_t)l*DMODEL, H);

      // 2. in_proj xi half -> XI
      gemm_nt<0><<<dim3(16, Mc/128), 256, 0, stream>>>(
          H, DMODEL, wl, DMODEL, XI, DINNER, DINNER, DMODEL, nullptr, nullptr, 0);

      // 3. causal conv + bias + SiLU: XI -> XC
      conv_silu_kernel<<<NB*4096, 256, 0, stream>>>(
          XI, cw + (size_t)l*DINNER*4, cb + (size_t)l*DINNER, XC);

      // 4. x_proj -> XD
      gemm_nt<0><<<dim3(1, Mc/128), 256, 0, stream>>>(
          XC, DINNER, xpw + (size_t)l*96*DINNER, DINNER, XD, 96, 96, DINNER,
          nullptr, nullptr, 0);

      // 5. dt_proj + bias + softplus -> XI (xi dead after conv)
      gemm_nt<1><<<dim3(16, Mc/128), 256, 0, stream>>>(
          XD, 96, dtw + (size_t)l*DINNER*64, 64, XI, DINNER, DINNER, 64,
          dtb + (size_t)l*DINNER, nullptr, 0);

      // 6. chunked selective scan: y (+u*D) in-place over XI
      scan_chunk<1><<<NB*NC*8, 256, 0, stream>>>(XC, XI, XD, Al, Dp + (size_t)l*DINNER, HF, SD);
      scan_prop    <<<NB*128,  256, 0, stream>>>(Al, HF, SD);
      scan_chunk<3><<<NB*NC*8, 256, 0, stream>>>(XC, XI, XD, Al, Dp + (size_t)l*DINNER, HF, SD);

      // 7. z-GEMM + gating: z = H x Wz^T, XC := y*silu(z)
      gemm_nt<2><<<dim3(16, Mc/128), 256, 0, stream>>>(
          H, DMODEL, wl + (size_t)DINNER*DMODEL, DMODEL, XC, DINNER,
          DINNER, DMODEL, nullptr, XI, DINNER);

      // 8. out_proj
      gemm_nt<0><<<dim3(8, Mc/128), 256, 0, stream>>>(
          XC, DINNER, ow + (size_t)l*DMODEL*DINNER, DINNER,
          (l==0) ? X1 : (outF + rowoff * DMODEL), DMODEL, DMODEL, DINNER,
          nullptr, nullptr, 0);
    }
  }
}

// Round 4
// 4329.787 us; speedup vs baseline: 2.3180x; 2.1827x over previous
//
#include <hip/hip_runtime.h>
#include <cstddef>
#include <cstdint>

// Problem constants (from reference)
#define SEQB   8
#define SEQL   2048
#define DMODEL 1024
#define DINNER 2048
#define DSTATE 16
#define MROWS  (SEQB*SEQL)   // 16384
#define NC     32            // scan chunks along t
#define TC     64            // SEQL/NC

typedef __attribute__((ext_vector_type(4))) float f32x4;
typedef __attribute__((ext_vector_type(8))) short bf16x8;

__device__ __forceinline__ float siluf(float x){ return x / (1.f + __expf(-x)); }
__device__ __forceinline__ float softplusf(float x){ return (x > 20.f) ? x : log1pf(__expf(x)); }

// RNE fp32 -> bf16 bits
__device__ __forceinline__ unsigned short f2bf_rne(float f){
  unsigned int u = __float_as_uint(f);
  u += 0x7FFFu + ((u>>16)&1u);
  return (unsigned short)(u>>16);
}
__device__ __forceinline__ void split_bf(float f, unsigned short& h, unsigned short& l){
  unsigned short hs = f2bf_rne(f);
  float hf = __uint_as_float(((unsigned int)hs)<<16);
  h = hs;
  l = f2bf_rne(f - hf);
}

// Convert 8 consecutive fp32 at PSRC into hi/lo bf16x8 and store to LDS.
#define CV8(PH, PL, PSRC) { \
  const float4* _p4 = (const float4*)(PSRC); \
  float4 _a = _p4[0], _b = _p4[1]; \
  bf16x8 _H, _L; unsigned short _h,_l; \
  split_bf(_a.x,_h,_l); _H[0]=(short)_h; _L[0]=(short)_l; \
  split_bf(_a.y,_h,_l); _H[1]=(short)_h; _L[1]=(short)_l; \
  split_bf(_a.z,_h,_l); _H[2]=(short)_h; _L[2]=(short)_l; \
  split_bf(_a.w,_h,_l); _H[3]=(short)_h; _L[3]=(short)_l; \
  split_bf(_b.x,_h,_l); _H[4]=(short)_h; _L[4]=(short)_l; \
  split_bf(_b.y,_h,_l); _H[5]=(short)_h; _L[5]=(short)_l; \
  split_bf(_b.z,_h,_l); _H[6]=(short)_h; _L[6]=(short)_l; \
  split_bf(_b.w,_h,_l); _H[7]=(short)_h; _L[7]=(short)_l; \
  *(bf16x8*)(PH) = _H; *(bf16x8*)(PL) = _L; }

// ---------------------------------------------------------------------------
// LayerNorm over last dim (1024), optional fused residual add (a + res).
// ---------------------------------------------------------------------------
__global__ __launch_bounds__(256)
void ln_kernel(const float* __restrict__ a, const float* __restrict__ res,
               const float* __restrict__ w, const float* __restrict__ bias,
               float* __restrict__ out)
{
  int row = blockIdx.x;
  size_t off = (size_t)row * DMODEL;
  float4 v = ((const float4*)(a + off))[threadIdx.x];
  if (res){
    float4 u = ((const float4*)(res + off))[threadIdx.x];
    v.x += u.x; v.y += u.y; v.z += u.z; v.w += u.w;
  }
  float s  = v.x + v.y + v.z + v.w;
  float s2 = fmaf(v.x,v.x, fmaf(v.y,v.y, fmaf(v.z,v.z, v.w*v.w)));
  #pragma unroll
  for (int o=32;o>0;o>>=1){ s += __shfl_down(s,o,64); s2 += __shfl_down(s2,o,64); }
  __shared__ float red[8];
  int lane = threadIdx.x & 63, wid = threadIdx.x >> 6;
  if (lane==0){ red[wid]=s; red[4+wid]=s2; }
  __syncthreads();
  s  = red[0]+red[1]+red[2]+red[3];
  s2 = red[4]+red[5]+red[6]+red[7];
  float mu  = s * (1.f/DMODEL);
  float var = s2 * (1.f/DMODEL) - mu*mu;
  float rstd = rsqrtf(var + 1e-5f);
  float4 wv = ((const float4*)w)[threadIdx.x];
  float4 bv = ((const float4*)bias)[threadIdx.x];
  float4 o4;
  o4.x = (v.x-mu)*rstd*wv.x + bv.x;
  o4.y = (v.y-mu)*rstd*wv.y + bv.y;
  o4.z = (v.z-mu)*rstd*wv.z + bv.z;
  o4.w = (v.w-mu)*rstd*wv.w + bv.w;
  ((float4*)(out + off))[threadIdx.x] = o4;
}

// ---------------------------------------------------------------------------
// Split-bf16 MFMA NT GEMM: C[m,n] = sum_k A[m,k]*B[n,k], fp32 in/out.
// 128x128 tile, BK=32, 256 thr (4 waves, each a 64x64 quadrant of 4x4 frags).
// Internally A,B split into hi/lo bf16; 3 MFMAs (hh, hl, lh) per frag pair
// accumulate into one fp32 acc -> ~fp32 precision.  M,N must be mult of 128.
// EPI==0: plain store   EPI==2: C = yb[m,n]*silu(C)
// ---------------------------------------------------------------------------
template<int EPI>
__global__ __launch_bounds__(256)
void mgemm(const float* __restrict__ A, int lda,
           const float* __restrict__ B, int ldb,
           float* __restrict__ C, int ldc, int K,
           const float* __restrict__ yb, int ldy)
{
  __shared__ __align__(16) unsigned short Ah[128][40], Al[128][40];
  __shared__ __align__(16) unsigned short Bh[128][40], Bl[128][40];
  const int t = threadIdx.x;
  const int mbase = blockIdx.y << 7, nbase = blockIdx.x << 7;
  const int srow = t >> 1, shalf = (t & 1) << 4;
  const float* pa = A + (size_t)(mbase + srow)*lda + shalf;
  const float* pb = B + (size_t)(nbase + srow)*ldb + shalf;

  const int lane = t & 63, w = t >> 6;
  const int wr = w >> 1, wc = w & 1;
  const int l16 = lane & 15, kq = lane >> 4;

  f32x4 acc[4][4];
  #pragma unroll
  for (int i=0;i<4;i++)
    #pragma unroll
    for (int j=0;j<4;j++) acc[i][j] = (f32x4){0.f,0.f,0.f,0.f};

  for (int k0 = 0; k0 < K; k0 += 32){
    CV8(&Ah[srow][shalf],   &Al[srow][shalf],   pa + k0);
    CV8(&Ah[srow][shalf+8], &Al[srow][shalf+8], pa + k0 + 8);
    CV8(&Bh[srow][shalf],   &Bl[srow][shalf],   pb + k0);
    CV8(&Bh[srow][shalf+8], &Bl[srow][shalf+8], pb + k0 + 8);
    __syncthreads();
    bf16x8 ah[4], al[4];
    #pragma unroll
    for (int mf=0; mf<4; mf++){
      int ar = wr*64 + mf*16 + l16;
      ah[mf] = *(const bf16x8*)&Ah[ar][kq*8];
      al[mf] = *(const bf16x8*)&Al[ar][kq*8];
    }
    #pragma unroll
    for (int nf=0; nf<4; nf++){
      int br = wc*64 + nf*16 + l16;
      bf16x8 bh = *(const bf16x8*)&Bh[br][kq*8];
      bf16x8 bl = *(const bf16x8*)&Bl[br][kq*8];
      #pragma unroll
      for (int mf=0; mf<4; mf++){
        acc[mf][nf] = __builtin_amdgcn_mfma_f32_16x16x32_bf16(ah[mf], bh, acc[mf][nf], 0,0,0);
        acc[mf][nf] = __builtin_amdgcn_mfma_f32_16x16x32_bf16(ah[mf], bl, acc[mf][nf], 0,0,0);
        acc[mf][nf] = __builtin_amdgcn_mfma_f32_16x16x32_bf16(al[mf], bh, acc[mf][nf], 0,0,0);
      }
    }
    __syncthreads();
  }

  #pragma unroll
  for (int mf=0; mf<4; mf++){
    int r0 = mbase + wr*64 + mf*16 + kq*4;
    #pragma unroll
    for (int nf=0; nf<4; nf++){
      int c = nbase + wc*64 + nf*16 + l16;
      #pragma unroll
      for (int r=0;r<4;r++){
        float v = acc[mf][nf][r];
        if (EPI==2){
          float yv = yb[(size_t)(r0+r)*ldy + c];
          v = yv * siluf(v);
        }
        C[(size_t)(r0+r)*ldc + c] = v;
      }
    }
  }
}

// ---------------------------------------------------------------------------
// x_proj MFMA kernel: XD[m, 0..95] = sum_k XC[m,k]*W[n,k].  K=2048.
// 32x96 tile -> Mc/32 blocks (full occupancy). 4 waves: wave w does m-frag
// (w&1) x 3 n-frags at cols (w>>1)*48. Split-bf16 3-pass as in mgemm.
// Threads 0..63 stage A (32 rows), 64..255 stage W (96 rows).
// ---------------------------------------------------------------------------
__global__ __launch_bounds__(256)
void xproj_mfma(const float* __restrict__ A,  // [M][2048]
                const float* __restrict__ W,  // [96][2048]
                float* __restrict__ XD)       // [M][96]
{
  __shared__ __align__(16) unsigned short Ah[32][40], Al[32][40];
  __shared__ __align__(16) unsigned short Bh[96][40], Bl[96][40];
  const int t = threadIdx.x;
  const int mbase = blockIdx.x << 5;
  const int lane = t & 63, w = t >> 6;
  const int mf = w & 1, nc0 = (w >> 1) * 48;
  const int l16 = lane & 15, kq = lane >> 4;
  const bool isA = (t < 64);
  const int srow = (isA ? t : (t - 64)) >> 1;
  const int shalf = (t & 1) << 4;
  const float* ps = isA ? (A + (size_t)(mbase + srow)*2048 + shalf)
                        : (W + (size_t)srow*2048 + shalf);
  unsigned short* dH = isA ? &Ah[srow][shalf] : &Bh[srow][shalf];
  unsigned short* dL = isA ? &Al[srow][shalf] : &Bl[srow][shalf];

  f32x4 acc[3];
  #pragma unroll
  for (int j=0;j<3;j++) acc[j] = (f32x4){0.f,0.f,0.f,0.f};

  for (int k0=0; k0<2048; k0+=32){
    CV8(dH,   dL,   ps + k0);
    CV8(dH+8, dL+8, ps + k0 + 8);
    __syncthreads();
    bf16x8 ah = *(const bf16x8*)&Ah[mf*16 + l16][kq*8];
    bf16x8 av = *(const bf16x8*)&Al[mf*16 + l16][kq*8];
    #pragma unroll
    for (int nf=0; nf<3; nf++){
      int br = nc0 + nf*16 + l16;
      bf16x8 bh = *(const bf16x8*)&Bh[br][kq*8];
      bf16x8 bl = *(const bf16x8*)&Bl[br][kq*8];
      acc[nf] = __builtin_amdgcn_mfma_f32_16x16x32_bf16(ah, bh, acc[nf], 0,0,0);
      acc[nf] = __builtin_amdgcn_mfma_f32_16x16x32_bf16(ah, bl, acc[nf], 0,0,0);
      acc[nf] = __builtin_amdgcn_mfma_f32_16x16x32_bf16(av, bh, acc[nf], 0,0,0);
    }
    __syncthreads();
  }
  #pragma unroll
  for (int nf=0; nf<3; nf++){
    int c = nc0 + nf*16 + l16;
    int r0 = mbase + mf*16 + kq*4;
    #pragma unroll
    for (int r=0;r<4;r++)
      XD[(size_t)(r0+r)*96 + c] = acc[nf][r];
  }
}

// ---------------------------------------------------------------------------
// fp32 NT GEMM (kept for dt_proj, K=64): C[m,n] = sum_k A[m,k]*B[n,k]
// EPI==1: C = softplus(C + ebias[n])
// ---------------------------------------------------------------------------
template<int EPI>
__global__ __launch_bounds__(256)
void gemm_nt(const float* __restrict__ A, int lda,
             const float* __restrict__ B, int ldb,
             float* __restrict__ C, int ldc,
             int N, int K,
             const float* __restrict__ ebias,
             const float* __restrict__ yb, int ldy)
{
  __shared__ float As[16][132];
  __shared__ float Bs[16][132];
  int tid = threadIdx.x;
  int tx = tid & 15, ty = tid >> 4;
  int mbase = blockIdx.y << 7;
  int nbase = blockIdx.x << 7;
  float acc[8][8];
  #pragma unroll
  for (int i=0;i<8;i++)
    #pragma unroll
    for (int j=0;j<8;j++) acc[i][j]=0.f;

  for (int k0=0;k0<K;k0+=16){
    #pragma unroll
    for (int it=0; it<2; it++){
      int idx = tid + (it<<8);
      int row = idx >> 2;
      int kq  = (idx & 3) << 2;
      float4 va = *(const float4*)(A + (size_t)(mbase+row)*lda + k0 + kq);
      As[kq+0][row]=va.x; As[kq+1][row]=va.y; As[kq+2][row]=va.z; As[kq+3][row]=va.w;
      int n = nbase + row;
      float4 vb = make_float4(0.f,0.f,0.f,0.f);
      if (n < N) vb = *(const float4*)(B + (size_t)n*ldb + k0 + kq);
      Bs[kq+0][row]=vb.x; Bs[kq+1][row]=vb.y; Bs[kq+2][row]=vb.z; Bs[kq+3][row]=vb.w;
    }
    __syncthreads();
    #pragma unroll
    for (int k=0;k<16;k++){
      float a[8], bb[8];
      *(float4*)&a[0]  = *(const float4*)&As[k][ty<<2];
      *(float4*)&a[4]  = *(const float4*)&As[k][64+(ty<<2)];
      *(float4*)&bb[0] = *(const float4*)&Bs[k][tx<<2];
      *(float4*)&bb[4] = *(const float4*)&Bs[k][64+(tx<<2)];
      #pragma unroll
      for (int i=0;i<8;i++)
        #pragma unroll
        for (int j=0;j<8;j++)
          acc[i][j] = fmaf(a[i], bb[j], acc[i][j]);
    }
    __syncthreads();
  }

  int n0 = nbase + (tx<<2);
  int n1 = n0 + 64;
  float4 eb0=make_float4(0,0,0,0), eb1=make_float4(0,0,0,0);
  if (EPI==1){
    if (n0 < N) eb0 = *(const float4*)(ebias + n0);
    if (n1 < N) eb1 = *(const float4*)(ebias + n1);
  }
  #pragma unroll
  for (int i=0;i<8;i++){
    int mrow = mbase + ((i<4) ? ((ty<<2)+i) : (64 + (ty<<2) + (i-4)));
    float4 c0 = make_float4(acc[i][0],acc[i][1],acc[i][2],acc[i][3]);
    float4 c1 = make_float4(acc[i][4],acc[i][5],acc[i][6],acc[i][7]);
    if (EPI==1){
      c0.x = softplusf(c0.x+eb0.x); c0.y = softplusf(c0.y+eb0.y);
      c0.z = softplusf(c0.z+eb0.z); c0.w = softplusf(c0.w+eb0.w);
      c1.x = softplusf(c1.x+eb1.x); c1.y = softplusf(c1.y+eb1.y);
      c1.z = softplusf(c1.z+eb1.z); c1.w = softplusf(c1.w+eb1.w);
    }
    if (EPI==2){
      if (n0 < N){
        float4 y0 = *(const float4*)(yb + (size_t)mrow*ldy + n0);
        c0.x = y0.x*siluf(c0.x); c0.y = y0.y*siluf(c0.y);
        c0.z = y0.z*siluf(c0.z); c0.w = y0.w*siluf(c0.w);
      }
      if (n1 < N){
        float4 y1 = *(const float4*)(yb + (size_t)mrow*ldy + n1);
        c1.x = y1.x*siluf(c1.x); c1.y = y1.y*siluf(c1.y);
        c1.z = y1.z*siluf(c1.z); c1.w = y1.w*siluf(c1.w);
      }
    }
    if (n0 < N) *(float4*)(C + (size_t)mrow*ldc + n0) = c0;
    if (n1 < N) *(float4*)(C + (size_t)mrow*ldc + n1) = c1;
  }
}

// ---------------------------------------------------------------------------
// Causal depthwise conv (k=4) + bias + SiLU.
// ---------------------------------------------------------------------------
__global__ __launch_bounds__(256)
void conv_silu_kernel(const float* __restrict__ xi, const float* __restrict__ cw,
                      const float* __restrict__ cb, float* __restrict__ xc)
{
  int idx = blockIdx.x*256 + threadIdx.x;
  int d = idx & (DINNER-1);
  int g = idx >> 11;
  int t0 = (g & 511) << 2;
  int b = g >> 9;
  float4 w4 = *(const float4*)(cw + d*4);
  float bias = cb[d];
  const float* base = xi + (size_t)b*SEQL*DINNER + d;
  float v[7];
  #pragma unroll
  for (int j=0;j<7;j++){
    int t = t0-3+j;
    v[j] = (t>=0) ? base[(size_t)t*DINNER] : 0.f;
  }
  float* outp = xc + ((size_t)b*SEQL + t0)*DINNER + d;
  #pragma unroll
  for (int j=0;j<4;j++){
    float y = fmaf(v[j+3], w4.w, fmaf(v[j+2], w4.z, fmaf(v[j+1], w4.y, fmaf(v[j], w4.x, bias))));
    outp[(size_t)j*DINNER] = siluf(y);
  }
}

// ---------------------------------------------------------------------------
// Chunked selective scan (PASS 1: local scan + hfin/sumdt; PASS 3: final).
// ---------------------------------------------------------------------------
template<int PASS>
__global__ __launch_bounds__(256)
void scan_chunk(const float* __restrict__ u_, float* __restrict__ dty,
                const float* __restrict__ xdbl,
                const float* __restrict__ A_log, const float* __restrict__ Dp,
                float* __restrict__ hfin, float* __restrict__ sumdt)
{
  int idx = blockIdx.x*256 + threadIdx.x;
  int d = idx & (DINNER-1);
  int g = idx >> 11;
  int c = g & (NC-1);
  int b = g >> 5;

  float A2[16];
  {
    const float* al = A_log + (size_t)d*DSTATE;
    #pragma unroll
    for (int s=0;s<16;s++) A2[s] = -expf(al[s]) * 1.44269504f;
  }
  float h[16];
  if (PASS == 1){
    #pragma unroll
    for (int s=0;s<16;s++) h[s] = 0.f;
  } else {
    const float* hp = hfin + ((size_t)g*DINNER + d)*16;
    #pragma unroll
    for (int s=0;s<16;s+=4) *(float4*)&h[s] = *(const float4*)(hp + s);
  }
  float Dv = (PASS==3) ? Dp[d] : 0.f;

  size_t row0 = (size_t)b*SEQL + (size_t)c*TC;
  const float* pu  = u_  + row0*DINNER + d;
  float*       pdt = dty + row0*DINNER + d;
  const float* pbc = xdbl + row0*96 + 64;

  float sdt = 0.f;
  float dt_n = pdt[0];
  float u_n  = pu[0];

  for (int t=0; t<TC; t++){
    float dtc = dt_n, uc = u_n;
    if (t+1 < TC){
      dt_n = pdt[(size_t)(t+1)*DINNER];
      u_n  = pu [(size_t)(t+1)*DINNER];
    }
    float Bv[16], Cv[16];
    {
      const float4* p4 = (const float4*)(pbc + (size_t)t*96);
      *(float4*)&Bv[0]=p4[0]; *(float4*)&Bv[4]=p4[1];
      *(float4*)&Bv[8]=p4[2]; *(float4*)&Bv[12]=p4[3];
      if (PASS==3){
        *(float4*)&Cv[0]=p4[4]; *(float4*)&Cv[4]=p4[5];
        *(float4*)&Cv[8]=p4[6]; *(float4*)&Cv[12]=p4[7];
      }
    }
    if (PASS==1) sdt += dtc;
    float du = dtc*uc;
    float y = 0.f;
    #pragma unroll
    for (int s=0;s<16;s++){
      float dA = exp2f(dtc*A2[s]);
      h[s] = fmaf(dA, h[s], du*Bv[s]);
      if (PASS==3) y = fmaf(h[s], Cv[s], y);
    }
    if (PASS==3){
      y = fmaf(uc, Dv, y);
      pdt[(size_t)t*DINNER] = y;
    }
  }

  if (PASS==1){
    float* hp = hfin + ((size_t)g*DINNER + d)*16;
    #pragma unroll
    for (int s=0;s<16;s+=4) *(float4*)(hp + s) = *(const float4*)&h[s];
    sumdt[(size_t)g*DINNER + d] = sdt;
  }
}

// ---------------------------------------------------------------------------
// Propagate chunk-initial states: in-place hfin[c] := H_init(c).
// ---------------------------------------------------------------------------
__global__ __launch_bounds__(256)
void scan_prop(const float* __restrict__ A_log, float* __restrict__ hfin,
               const float* __restrict__ sumdt)
{
  int idx = blockIdx.x*256 + threadIdx.x;
  int s = idx & 15;
  int d = (idx >> 4) & (DINNER-1);
  int b = idx >> 15;
  float A2 = -expf(A_log[(size_t)d*DSTATE + s]) * 1.44269504f;
  float H = 0.f;
  size_t hbase = ((size_t)b*NC*DINNER + d)*16 + s;
  size_t sbase = (size_t)b*NC*DINNER + d;
  for (int c=0;c<NC;c++){
    float P   = exp2f(A2 * sumdt[sbase + (size_t)c*DINNER]);
    float tmp = hfin[hbase + (size_t)c*DINNER*16];
    hfin[hbase + (size_t)c*DINNER*16] = H;
    H = fmaf(P, H, tmp);
  }
}

// ---------------------------------------------------------------------------
// Launcher (workspace-adaptive, NB batches per chunk).
// ---------------------------------------------------------------------------
extern "C" void kernel_launch(void* const* d_in, const int* in_sizes, int n_in,
                              void* d_out, int out_size, void* d_ws, size_t ws_size,
                              hipStream_t stream)
{
  const float* x    = (const float*)d_in[0];
  const float* in_w = (const float*)d_in[1];
  const float* cw   = (const float*)d_in[2];
  const float* cb   = (const float*)d_in[3];
  const float* xpw  = (const float*)d_in[4];
  const float* dtw  = (const float*)d_in[5];
  const float* dtb  = (const float*)d_in[6];
  const float* A_log= (const float*)d_in[7];
  const float* Dp   = (const float*)d_in[8];
  const float* ow   = (const float*)d_in[9];
  const float* nw   = (const float*)d_in[10];
  const float* nb   = (const float*)d_in[11];
  float* outF = (float*)d_out;

  // Per-batch scratch: 2*2048*2048*4 + 2048*96*4 + 2048*1024*4 = 76,283,904 B
  int NB = 8;
  while (NB > 1 && (size_t)NB * 76283904ULL > ws_size) NB >>= 1;
  const int Mc = NB * SEQL;
  const int nchunk = SEQB / NB;

  float* ws = (float*)d_ws;
  float* XI = ws;                                   // Mc*2048 (xi -> dt -> y)
  float* XC = XI + (size_t)Mc*DINNER;               // Mc*2048 (u -> gated y)
  float* XD = XC + (size_t)Mc*DINNER;               // Mc*96   (dt_low|B|C)
  float* X1 = XD + (size_t)Mc*96;                   // Mc*1024 (layer-0 out)
  float* HF = X1;                                   // aliases X1 (dead then)
  float* SD = HF + (size_t)Mc*512;                  // Mc*32   (sumdt)

  for (int c = 0; c < nchunk; ++c){
    const size_t rowoff = (size_t)c * Mc;
    const float* xrows = x + rowoff * DMODEL;
    float* H = outF + rowoff * DMODEL;              // d_out doubles as LN buf

    for (int l = 0; l < 2; ++l){
      const float* wl = in_w + (size_t)l*2*DINNER*DMODEL;
      const float* Al = A_log + (size_t)l*DINNER*DSTATE;

      // 1. LayerNorm (+ residual for layer 1)
      ln_kernel<<<Mc, 256, 0, stream>>>(
          (l==0) ? xrows : X1, (l==0) ? nullptr : xrows,
          nw + (size_t)l*DMODEL, nb + (size_t)l*DMODEL, H);

      // 2. in_proj xi half (split-bf16 MFMA) -> XI
      mgemm<0><<<dim3(DINNER/128, Mc/128), 256, 0, stream>>>(
          H, DMODEL, wl, DMODEL, XI, DINNER, DMODEL, nullptr, 0);

      // 3. causal conv + bias + SiLU: XI -> XC
      conv_silu_kernel<<<NB*4096, 256, 0, stream>>>(
          XI, cw + (size_t)l*DINNER*4, cb + (size_t)l*DINNER, XC);

      // 4. x_proj (MFMA, 32x96 tiles) -> XD
      xproj_mfma<<<Mc/32, 256, 0, stream>>>(
          XC, xpw + (size_t)l*96*DINNER, XD);

      // 5. dt_proj + bias + softplus (fp32, K=64) -> XI
      gemm_nt<1><<<dim3(16, Mc/128), 256, 0, stream>>>(
          XD, 96, dtw + (size_t)l*DINNER*64, 64, XI, DINNER, DINNER, 64,
          dtb + (size_t)l*DINNER, nullptr, 0);

      // 6. chunked selective scan: y (+u*D) in-place over XI
      scan_chunk<1><<<NB*NC*8, 256, 0, stream>>>(XC, XI, XD, Al, Dp + (size_t)l*DINNER, HF, SD);
      scan_prop    <<<NB*128,  256, 0, stream>>>(Al, HF, SD);
      scan_chunk<3><<<NB*NC*8, 256, 0, stream>>>(XC, XI, XD, Al, Dp + (size_t)l*DINNER, HF, SD);

      // 7. z-GEMM + gating (split-bf16 MFMA): XC := y*silu(z)
      mgemm<2><<<dim3(DINNER/128, Mc/128), 256, 0, stream>>>(
          H, DMODEL, wl + (size_t)DINNER*DMODEL, DMODEL, XC, DINNER, DMODEL,
          XI, DINNER);

      // 8. out_proj (split-bf16 MFMA)
      mgemm<0><<<dim3(DMODEL/128, Mc/128), 256, 0, stream>>>(
          XC, DINNER, ow + (size_t)l*DMODEL*DINNER, DINNER,
          (l==0) ? X1 : (outF + rowoff * DMODEL), DMODEL, DINNER,
          nullptr, 0);
    }
  }
}